// Round 8
// baseline (184.868 us; speedup 1.0000x reference)
//
#include <hip/hip_runtime.h>

#define N_NODE 200
#define T_LEN 360
#define T_POOL 350
#define T_PAD 384
#define P_PAT 400
#define P_PAD 512
#define NWIN 14
#define STRIDE_ 25
#define KPAD 224            // 7 stages x 32

// ---- workspace layout (bytes); total ~26.2 MB ----
#define O_AH    0           // A, MFMA-frag order: [7][8][4][64][8] bf16 = 229376
#define O_XT    229376      // XbfT [128][384][224] bf16 = 22020096 (t-major, k-contig)
#define O_INVN  22249472    // [128][384] f32 = 196608
#define O_POS   22446080    // [128][512][14] u32 = 3670016 (zeroed in k_prep)
#define O_TOPN  26116096    // [400][3] i32
#define O_TOPV  26120896    // [400][3] f32
#define O_NORMT 26125696    // [400] f32
#define O_CTR   26127296    // [128] u32

typedef unsigned short u16;
typedef __attribute__((ext_vector_type(8))) short bf16x8;
typedef __attribute__((ext_vector_type(4))) float f32x4;

__device__ __forceinline__ unsigned fkey(float f) {
    unsigned u = __float_as_uint(f);
    return (u & 0x80000000u) ? ~u : (u | 0x80000000u);
}
__device__ __forceinline__ u16 f2bf(float f) {          // RNE f32->bf16
    unsigned u = __float_as_uint(f);
    unsigned r = u + 0x7FFFu + ((u >> 16) & 1u);
    return (u16)(r >> 16);
}

// ---- prep: pos/ctr zero + pattern prep (blk<128) + X convert/transpose (blk>=128) ----
__global__ __launch_bounds__(256) void k_prep(
    const float* __restrict__ x, const int* __restrict__ length,
    const float* __restrict__ pat,
    u16* __restrict__ Ah, u16* __restrict__ XT, float* __restrict__ invn,
    int* __restrict__ topn_w, float* __restrict__ topv_w, float* __restrict__ normt,
    unsigned* __restrict__ pos, unsigned* __restrict__ ctr)
{
    __shared__ unsigned ldsw[2176];       // [128][17] u32 (pitch 17 -> conflict-free)
    int blk = blockIdx.x, tid = threadIdx.x;

    {   // zero pos: 512*256*7 = 917504 u32 exactly
        int base = blk * 256 + tid;
        #pragma unroll
        for (int i = 0; i < 7; ++i) pos[base + i * 131072] = 0u;
    }
    if (blk == 0 && tid < 128) ctr[tid] = 0u;

    if (blk < 128) {
        // ---- pattern prep: 4 waves, one pattern each ----
        int lane = tid & 63;
        int p = blk * 4 + (tid >> 6);     // 0..511
        bool pv = p < P_PAT;
        float sv[4], av[4];
        int nn[4];
        float ss = 0.f;
        #pragma unroll
        for (int j = 0; j < 4; ++j) {
            int n = lane + 64 * j;
            nn[j] = n;
            if (pv && n < N_NODE) { float v = pat[p * N_NODE + n]; sv[j] = v; av[j] = fabsf(v); ss += v * v; }
            else { sv[j] = 0.f; av[j] = -1.f; }
        }
        #pragma unroll
        for (int off = 32; off >= 1; off >>= 1) ss += __shfl_xor(ss, off);
        float rn = 1.0f / sqrtf(ss + 1e-9f);

        int pb = p >> 6, ii = (p >> 4) & 3, plm = p & 15;
        #pragma unroll
        for (int j = 0; j < 4; ++j) {
            int n = nn[j];
            if (n < KPAD) {
                float v = (pv && n < N_NODE) ? sv[j] * rn : 0.f;
                int s = n >> 5, c = n & 31, quad = c >> 3, e = c & 7;
                size_t idx = ((size_t)((s * 8 + pb) * 4 + ii) * 64 + quad * 16 + plm) * 8 + e;
                Ah[idx] = f2bf(v);
            }
        }
        if (!pv) return;

        int topn[3]; float topv[3];
        for (int r = 0; r < 3; ++r) {
            float bv = -2.f; int bi = 1 << 30;
            #pragma unroll
            for (int j = 0; j < 4; ++j)
                if (av[j] > bv || (av[j] == bv && nn[j] < bi)) { bv = av[j]; bi = nn[j]; }
            #pragma unroll
            for (int off = 32; off >= 1; off >>= 1) {
                float ov = __shfl_xor(bv, off); int oi = __shfl_xor(bi, off);
                if (ov > bv || (ov == bv && oi < bi)) { bv = ov; bi = oi; }
            }
            int jj = bi >> 6, src = bi & 63;
            float rawj = (jj == 0) ? sv[0] : (jj == 1) ? sv[1] : (jj == 2) ? sv[2] : sv[3];
            float raw = __shfl(rawj, src);
            topn[r] = bi; topv[r] = raw * rn;
            #pragma unroll
            for (int j = 0; j < 4; ++j) if (nn[j] == bi) av[j] = -1.f;
        }
        float fullnorm = sqrtf(ss) * rn;
        float topnorm = sqrtf(topv[0]*topv[0] + topv[1]*topv[1] + topv[2]*topv[2]);
        if (lane == 0) {
            float d = 1.0f - topnorm / fullnorm;
            normt[p] = d * d * (1.0f / 800.0f);
        }
        if (lane < 3) { topn_w[p * 3 + lane] = topn[lane]; topv_w[p * 3 + lane] = topv[lane]; }
        return;
    }

    // ---- X convert + transpose: block -> (b, t-tile of 128) ----
    int b1 = blk - 128;                   // 0..383
    int b = b1 / 3, ti = b1 - 3 * b;
    int t0 = ti * 128;
    int th = tid & 127, cg = tid >> 7;    // t-lane, cc-group
    int t = t0 + th;
    bool tok = t < T_LEN;
    const float* xb = x + (size_t)b * (N_NODE * T_LEN);
    float ssq = 0.f;

    for (int c = 0; c < 7; ++c) {
        int k0 = c * 32;
        #pragma unroll
        for (int cc8 = 0; cc8 < 8; ++cc8) {
            int cc = cg * 8 + cc8;        // u32 column 0..15
            int k = k0 + cc * 2;
            float v0 = (tok && k     < N_NODE) ? xb[k * T_LEN + t]       : 0.f;
            float v1 = (tok && k + 1 < N_NODE) ? xb[(k + 1) * T_LEN + t] : 0.f;
            ssq = fmaf(v0, v0, fmaf(v1, v1, ssq));
            ldsw[th * 17 + cc] = (unsigned)f2bf(v0) | ((unsigned)f2bf(v1) << 16);
        }
        __syncthreads();
        {   // write out: thread -> (t2, h): 16B = 8 k
            int t2 = tid >> 1, h = tid & 1;
            unsigned w0 = ldsw[t2 * 17 + h * 4 + 0];
            unsigned w1 = ldsw[t2 * 17 + h * 4 + 1];
            unsigned w2 = ldsw[t2 * 17 + h * 4 + 2];
            unsigned w3 = ldsw[t2 * 17 + h * 4 + 3];
            uint4 val = make_uint4(w0, w1, w2, w3);
            *(uint4*)&XT[(size_t)(b * T_PAD + t0 + t2) * KPAD + k0 + h * 8] = val;
        }
        __syncthreads();
    }
    // reduce ssq pairs, write invn (validity + 1/sap folded)
    ((float*)ldsw)[tid] = ssq;
    __syncthreads();
    if (tid < 128) {
        float tot = ((float*)ldsw)[tid] + ((float*)ldsw)[tid + 128];
        int sap = length[b] / STRIDE_;
        int tvalid = sap * STRIDE_;
        float iv = (t0 + tid < tvalid) ? 1.0f / (sqrtf(tot + 1e-9f) * (float)sap) : 0.f;
        invn[b * T_PAD + t0 + tid] = iv;
    }
}

// ---- fused: barrier-free MFMA K-loop (frags direct from global) + pooling + tail classifier ----
#define LDS_SS 0            // 16*132*4 = 8448 (epilogue)
#define LDS_MASK 0          // tail: maskT 2600 u32 = 10400 (aliases Ss, dead by then)
#define LDS_CF0 10400
#define LDS_CF1 12000
#define LDS_SH  13600       // 512 f32 = 2048
#define LDS_FLAG 15648
__global__ __launch_bounds__(256) void k_all(
    const u16* __restrict__ Ah, const u16* __restrict__ XT,
    const float* __restrict__ invn, unsigned* __restrict__ pos,
    unsigned* __restrict__ ctr,
    const int* __restrict__ topn_w, const float* __restrict__ topv_w,
    const float* __restrict__ W, const float* __restrict__ normt,
    const float* __restrict__ bcls, float* __restrict__ out)
{
    __shared__ __align__(16) char smem[15664];
    int tid = threadIdx.x, blk = blockIdx.x;
    // XCD co-location: 12 blocks of each b are congruent mod 8
    int xcd = blk & 7, slot = blk >> 3;       // slot 0..191
    int g = slot / 12, r = slot - 12 * g;     // g 0..15
    int b = xcd + 8 * g;
    int t0 = (r % 3) * 128;
    int p0 = (r / 3) * 128;
    int lane = tid & 63, wid = tid >> 6;
    int quad = lane >> 4, lm = lane & 15;
    int wp = wid >> 1, wt = wid & 1;
    int pbq = (p0 >> 6) + wp;

    f32x4 acc[4][4];
    #pragma unroll
    for (int i = 0; i < 4; ++i)
        #pragma unroll
        for (int j = 0; j < 4; ++j) acc[i][j] = (f32x4){0.f, 0.f, 0.f, 0.f};

    const u16* Abase = Ah + (size_t)pbq * 2048 + lane * 8;       // + s*16384 + i*512
    const u16* Xbase[4];
    #pragma unroll
    for (int j = 0; j < 4; ++j)
        Xbase[j] = XT + (size_t)(b * T_PAD + t0 + wt * 64 + j * 16 + lm) * KPAD + quad * 8;

    // register-double-buffered, barrier-free K-loop
    bf16x8 aC[4], xC[4], aN[4], xN[4];
    #pragma unroll
    for (int i = 0; i < 4; ++i) aC[i] = *(const bf16x8*)(Abase + i * 512);
    #pragma unroll
    for (int j = 0; j < 4; ++j) xC[j] = *(const bf16x8*)(Xbase[j]);
    #pragma unroll
    for (int s = 0; s < 7; ++s) {
        if (s < 6) {
            #pragma unroll
            for (int i = 0; i < 4; ++i) aN[i] = *(const bf16x8*)(Abase + (s + 1) * 16384 + i * 512);
            #pragma unroll
            for (int j = 0; j < 4; ++j) xN[j] = *(const bf16x8*)(Xbase[j] + (s + 1) * 32);
        }
        #pragma unroll
        for (int i = 0; i < 4; ++i)
            #pragma unroll
            for (int j = 0; j < 4; ++j)
                acc[i][j] = __builtin_amdgcn_mfma_f32_16x16x32_bf16(aC[i], xC[j], acc[i][j], 0, 0, 0);
        #pragma unroll
        for (int i = 0; i < 4; ++i) aC[i] = aN[i];
        #pragma unroll
        for (int j = 0; j < 4; ++j) xC[j] = xN[j];
    }

    // per-column scale (validity + 1/sap + frame-norm) straight from global
    float invv[4];
    #pragma unroll
    for (int j = 0; j < 4; ++j) invv[j] = invn[b * T_PAD + t0 + wt * 64 + j * 16 + lm];

    // epilogue: 4 rounds x 32 p-rows -> windowed max -> atomicMax(pos)
    float* Ss = (float*)&smem[LDS_SS];
    int wbase = t0 / STRIDE_;
    int tmax = min(t0 + 128, T_POOL);
    for (int rr = 0; rr < 4; ++rr) {
        __syncthreads();
        if (wp == (rr >> 1)) {
            #pragma unroll
            for (int i2 = 0; i2 < 2; ++i2) {
                int i = (rr & 1) * 2 + i2;
                #pragma unroll
                for (int j = 0; j < 4; ++j) {
                    int col = wt * 64 + j * 16 + lm;
                    #pragma unroll
                    for (int q = 0; q < 4; ++q)
                        Ss[(i2 * 16 + quad * 4 + q) * 132 + col] = acc[i][j][q] * invv[j];
                }
            }
        }
        __syncthreads();
        int sidx = tid & 7, pl = tid >> 3;
        int w = wbase + sidx;
        int tlo = max(w * STRIDE_, t0), thi = min(w * STRIDE_ + STRIDE_, tmax);
        if (w < NWIN && tlo < thi) {
            float m = -3.4e38f;
            for (int t = tlo; t < thi; ++t) m = fmaxf(m, Ss[pl * 132 + (t - t0)]);
            atomicMax(&pos[((size_t)b * P_PAD + p0 + rr * 32 + pl) * NWIN + w], fkey(m));
        }
    }

    // ---- last-arrival gate: 12th block of this b runs the classifier ----
    __syncthreads();
    volatile int* flagp = (volatile int*)&smem[LDS_FLAG];
    if (tid == 0) {
        __threadfence();
        unsigned old = atomicAdd(&ctr[b], 1u);
        *flagp = (old == 11u) ? 1 : 0;
    }
    __syncthreads();
    int flag = *flagp;
    __syncthreads();                     // all read flag before smem reuse
    if (!flag) return;
    __threadfence();                     // acquire: see all 12 blocks' pos writes

    unsigned* maskT = (unsigned*)&smem[LDS_MASK];   // [200][13] bitmask
    float* cf0 = (float*)&smem[LDS_CF0];
    float* cf1 = (float*)&smem[LDS_CF1];
    float* sh  = (float*)&smem[LDS_SH];
    for (int i = tid; i < N_NODE * 13; i += 256) maskT[i] = 0u;
    __syncthreads();
    for (int idx = tid; idx < P_PAT * 3; idx += 256) {
        int q = idx / 3;
        int n = topn_w[idx];
        atomicOr(&maskT[n * 13 + (q >> 5)], 1u << (q & 31));
    }
    __syncthreads();
    for (int p = tid; p < P_PAT; p += 256) {
        int tn[3]; float tv[3];
        #pragma unroll
        for (int i = 0; i < 3; ++i) { tn[i] = topn_w[p * 3 + i]; tv[i] = topv_w[p * 3 + i]; }
        float c0 = 0.f, c1 = 0.f;
        #pragma unroll
        for (int i = 0; i < 3; ++i)
            #pragma unroll
            for (int j = 0; j < 3; ++j) {
                int a = tn[i], bb = tn[j];
                int mgv = 0;
                #pragma unroll
                for (int w = 0; w < 13; ++w)
                    mgv += __popc(maskT[a * 13 + w] & maskT[bb * 13 + w]);
                int nm = a * N_NODE + bb;
                float f = tv[i] * tv[j] / ((float)mgv + 1e-9f);
                c0 += f * W[nm * 2 + 0];
                c1 += f * W[nm * 2 + 1];
            }
        cf0[p] = c0; cf1[p] = c1;
    }
    __syncthreads();
    float s0 = 0.f, s1 = 0.f;
    for (int p = tid; p < P_PAT; p += 256) {
        const unsigned* pp = pos + ((size_t)b * P_PAD + p) * NWIN;
        float fs = 0.f;
        #pragma unroll
        for (int w = 0; w < NWIN; ++w) {
            unsigned k = pp[w];
            unsigned u = (k & 0x80000000u) ? (k ^ 0x80000000u) : ~k;
            fs += __uint_as_float(u);
        }
        s0 += fs * cf0[p];
        s1 += fs * cf1[p];
    }
    sh[tid] = s0; sh[256 + tid] = s1;
    __syncthreads();
    for (int o = 128; o > 0; o >>= 1) {
        if (tid < o) { sh[tid] += sh[tid + o]; sh[256 + tid] += sh[256 + tid + o]; }
        __syncthreads();
    }
    if (tid == 0) {
        out[b * 2 + 0] = sh[0]   + bcls[0];
        out[b * 2 + 1] = sh[256] + bcls[1];
    }
    if (b == 0) {
        __syncthreads();
        float ns = 0.f;
        for (int i = tid; i < P_PAT; i += 256) ns += normt[i];
        sh[tid] = ns;
        __syncthreads();
        for (int o = 128; o > 0; o >>= 1) {
            if (tid < o) sh[tid] += sh[tid + o];
            __syncthreads();
        }
        if (tid == 0) { out[256] = sh[0]; out[257] = 0.f; }
    }
}

extern "C" void kernel_launch(void* const* d_in, const int* in_sizes, int n_in,
                              void* d_out, int out_size, void* d_ws, size_t ws_size,
                              hipStream_t stream) {
    (void)in_sizes; (void)n_in; (void)out_size; (void)ws_size;
    const float* x        = (const float*)d_in[0];
    const int*   length   = (const int*)d_in[1];
    const float* patterns = (const float*)d_in[2];
    const float* Wcls     = (const float*)d_in[3];
    const float* bcls     = (const float*)d_in[4];
    float* out = (float*)d_out;
    char* ws = (char*)d_ws;

    u16*      Ah    = (u16*)(ws + O_AH);
    u16*      XT    = (u16*)(ws + O_XT);
    float*    invn  = (float*)(ws + O_INVN);
    unsigned* pos   = (unsigned*)(ws + O_POS);
    int*      topn  = (int*)(ws + O_TOPN);
    float*    topv  = (float*)(ws + O_TOPV);
    float*    normt = (float*)(ws + O_NORMT);
    unsigned* ctr   = (unsigned*)(ws + O_CTR);

    k_prep<<<512, 256, 0, stream>>>(x, length, patterns, Ah, XT, invn,
                                    topn, topv, normt, pos, ctr);
    k_all<<<1536, 256, 0, stream>>>(Ah, XT, invn, pos, ctr,
                                    topn, topv, Wcls, normt, bcls, out);
}

// Round 9
// 136.626 us; speedup vs baseline: 1.3531x; 1.3531x over previous
//
#include <hip/hip_runtime.h>

#define N_NODE 200
#define T_LEN 360
#define T_POOL 350
#define T_PAD 384
#define P_PAT 400
#define P_PAD 512
#define NWIN 14
#define STRIDE_ 25
#define KPAD 224            // 7 stages x 32

// ---- workspace layout (bytes) ----
#define O_AH    0           // A, MFMA-frag order: [7][8][4][64][8] bf16 = 229376
#define O_XT    229376      // X, B-frag order: [128][6][7][4][4][16][8] bf16 = 22020096
#define O_INVN  22249472    // [128][384] f32 = 196608
#define O_POS   22446080    // [128][512][14] u32 = 3670016 (zeroed in k_prep)
#define O_TOPN  26116096    // [400][3] i32
#define O_TOPV  26120896    // [400][3] f32
#define O_NORMT 26125696    // [400] f32

typedef unsigned short u16;
typedef __attribute__((ext_vector_type(8))) short bf16x8;
typedef __attribute__((ext_vector_type(4))) float f32x4;

__device__ __forceinline__ unsigned fkey(float f) {
    unsigned u = __float_as_uint(f);
    return (u & 0x80000000u) ? ~u : (u | 0x80000000u);
}
__device__ __forceinline__ u16 f2bf(float f) {          // RNE f32->bf16
    unsigned u = __float_as_uint(f);
    unsigned r = u + 0x7FFFu + ((u >> 16) & 1u);
    return (u16)(r >> 16);
}

// ---- prep: pos zero + pattern prep (blk<128) + X convert/transpose to frag order ----
__global__ __launch_bounds__(256) void k_prep(
    const float* __restrict__ x, const int* __restrict__ length,
    const float* __restrict__ pat,
    u16* __restrict__ Ah, u16* __restrict__ XT, float* __restrict__ invn,
    int* __restrict__ topn_w, float* __restrict__ topv_w, float* __restrict__ normt,
    unsigned* __restrict__ pos)
{
    __shared__ unsigned ldsw[2176];       // [128][17] u32 (pitch 17)
    int blk = blockIdx.x, tid = threadIdx.x;

    {   // zero pos: 512*256*7 = 917504 u32 exactly
        int base = blk * 256 + tid;
        #pragma unroll
        for (int i = 0; i < 7; ++i) pos[base + i * 131072] = 0u;
    }

    if (blk < 128) {
        // ---- pattern prep: 4 waves, one pattern each ----
        int lane = tid & 63;
        int p = blk * 4 + (tid >> 6);     // 0..511
        bool pv = p < P_PAT;
        float sv[4], av[4];
        int nn[4];
        float ss = 0.f;
        #pragma unroll
        for (int j = 0; j < 4; ++j) {
            int n = lane + 64 * j;
            nn[j] = n;
            if (pv && n < N_NODE) { float v = pat[p * N_NODE + n]; sv[j] = v; av[j] = fabsf(v); ss += v * v; }
            else { sv[j] = 0.f; av[j] = -1.f; }
        }
        #pragma unroll
        for (int off = 32; off >= 1; off >>= 1) ss += __shfl_xor(ss, off);
        float rn = 1.0f / sqrtf(ss + 1e-9f);

        int pb = p >> 6, ii = (p >> 4) & 3, plm = p & 15;
        #pragma unroll
        for (int j = 0; j < 4; ++j) {
            int n = nn[j];
            if (n < KPAD) {
                float v = (pv && n < N_NODE) ? sv[j] * rn : 0.f;
                int s = n >> 5, c = n & 31, quad = c >> 3, e = c & 7;
                size_t idx = ((size_t)((s * 8 + pb) * 4 + ii) * 64 + quad * 16 + plm) * 8 + e;
                Ah[idx] = f2bf(v);
            }
        }
        if (!pv) return;

        int topn[3]; float topv[3];
        for (int r = 0; r < 3; ++r) {
            float bv = -2.f; int bi = 1 << 30;
            #pragma unroll
            for (int j = 0; j < 4; ++j)
                if (av[j] > bv || (av[j] == bv && nn[j] < bi)) { bv = av[j]; bi = nn[j]; }
            #pragma unroll
            for (int off = 32; off >= 1; off >>= 1) {
                float ov = __shfl_xor(bv, off); int oi = __shfl_xor(bi, off);
                if (ov > bv || (ov == bv && oi < bi)) { bv = ov; bi = oi; }
            }
            int jj = bi >> 6, src = bi & 63;
            float rawj = (jj == 0) ? sv[0] : (jj == 1) ? sv[1] : (jj == 2) ? sv[2] : sv[3];
            float raw = __shfl(rawj, src);
            topn[r] = bi; topv[r] = raw * rn;
            #pragma unroll
            for (int j = 0; j < 4; ++j) if (nn[j] == bi) av[j] = -1.f;
        }
        float fullnorm = sqrtf(ss) * rn;
        float topnorm = sqrtf(topv[0]*topv[0] + topv[1]*topv[1] + topv[2]*topv[2]);
        if (lane == 0) {
            float d = 1.0f - topnorm / fullnorm;
            normt[p] = d * d * (1.0f / 800.0f);
        }
        if (lane < 3) { topn_w[p * 3 + lane] = topn[lane]; topv_w[p * 3 + lane] = topv[lane]; }
        return;
    }

    // ---- X convert + transpose: block -> (b, t-tile of 128) ----
    int b1 = blk - 128;                   // 0..383
    int b = b1 / 3, ti = b1 - 3 * b;
    int t0 = ti * 128;
    int th = tid & 127, cg = tid >> 7;    // fill coords
    int t = t0 + th;
    bool tok = t < T_LEN;
    const float* xb = x + (size_t)b * (N_NODE * T_LEN);
    float ssq = 0.f;

    // write-out coords (frag order)
    int t2 = tid & 127, qh = tid >> 7;
    int tbw = (t0 + t2) >> 6;
    int jjw = (t2 >> 4) & 3;
    int lmw = t2 & 15;

    for (int c = 0; c < 7; ++c) {
        int k0 = c * 32;
        #pragma unroll
        for (int cc8 = 0; cc8 < 8; ++cc8) {
            int cc = cg * 8 + cc8;        // u32 column 0..15
            int k = k0 + cc * 2;
            float v0 = (tok && k     < N_NODE) ? xb[k * T_LEN + t]       : 0.f;
            float v1 = (tok && k + 1 < N_NODE) ? xb[(k + 1) * T_LEN + t] : 0.f;
            ssq = fmaf(v0, v0, fmaf(v1, v1, ssq));
            ldsw[th * 17 + cc] = (unsigned)f2bf(v0) | ((unsigned)f2bf(v1) << 16);
        }
        __syncthreads();
        {   // frag-order write: [b][tbw][c(s)][jjw][q][lmw][8k]; ALL 4 q-octets covered
            size_t rowbase = (size_t)(b * 6 + tbw) * 14336 + (size_t)(c * 4 + jjw) * 512 + lmw * 8;
            #pragma unroll
            for (int u = 0; u < 2; ++u) {
                int q = qh + 2 * u;
                uint4 val = make_uint4(ldsw[t2 * 17 + q * 4 + 0], ldsw[t2 * 17 + q * 4 + 1],
                                       ldsw[t2 * 17 + q * 4 + 2], ldsw[t2 * 17 + q * 4 + 3]);
                *(uint4*)&XT[rowbase + q * 128] = val;
            }
        }
        __syncthreads();
    }
    // reduce ssq pairs, write invn (validity + 1/sap folded)
    ((float*)ldsw)[tid] = ssq;
    __syncthreads();
    if (tid < 128) {
        float tot = ((float*)ldsw)[tid] + ((float*)ldsw)[tid + 128];
        int sap = length[b] / STRIDE_;
        int tvalid = sap * STRIDE_;
        float iv = (t0 + tid < tvalid) ? 1.0f / (sqrtf(tot + 1e-9f) * (float)sap) : 0.f;
        invn[b * T_PAD + t0 + tid] = iv;
    }
}

// ---- MFMA GEMM: barrier-free K-loop, all frags coalesced 1KB/wave from global ----
__global__ __launch_bounds__(256, 2) void k_mm(
    const u16* __restrict__ Ah, const u16* __restrict__ XT,
    const float* __restrict__ invn, unsigned* __restrict__ pos)
{
    __shared__ __align__(16) float Ss[16 * 132];
    int tid = threadIdx.x, blk = blockIdx.x;
    // XCD co-location: 12 blocks of each b congruent mod 8
    int xcd = blk & 7, slot = blk >> 3;
    int g = slot / 12, r = slot - 12 * g;
    int b = xcd + 8 * g;
    int t0 = (r % 3) * 128;
    int p0 = (r / 3) * 128;
    int lane = tid & 63, wid = tid >> 6;
    int quad = lane >> 4, lm = lane & 15;
    int wp = wid >> 1, wt = wid & 1;
    int pbq = (p0 >> 6) + wp;
    int tb = (t0 >> 6) + wt;

    const u16* Ab = Ah + (size_t)pbq * 2048 + lane * 8;           // + s*16384 + i*512
    const u16* Xb = XT + (size_t)(b * 6 + tb) * 14336 + lane * 8; // + (s*4+j)*512

    f32x4 acc[4][4];
    #pragma unroll
    for (int i = 0; i < 4; ++i)
        #pragma unroll
        for (int j = 0; j < 4; ++j) acc[i][j] = (f32x4){0.f, 0.f, 0.f, 0.f};

    auto LA = [&](bf16x8* d, int s) {
        const u16* p = Ab + (size_t)s * 16384;
        #pragma unroll
        for (int i = 0; i < 4; ++i) d[i] = *(const bf16x8*)(p + i * 512);
    };
    auto MM = [&](bf16x8* a, bf16x8* xv) {
        #pragma unroll
        for (int i = 0; i < 4; ++i)
            #pragma unroll
            for (int j = 0; j < 4; ++j)
                acc[i][j] = __builtin_amdgcn_mfma_f32_16x16x32_bf16(a[i], xv[j], acc[i][j], 0, 0, 0);
    };

    bf16x8 a0[4], a1[4], xf[16], xg[12];
    LA(a0, 0);
    #pragma unroll
    for (int s = 0; s < 4; ++s)
        #pragma unroll
        for (int j = 0; j < 4; ++j) xf[s * 4 + j] = *(const bf16x8*)(Xb + (s * 4 + j) * 512);
    LA(a1, 1);
    MM(a0, &xf[0]);                  // stage 0
    LA(a0, 2);
    MM(a1, &xf[4]);                  // stage 1
    #pragma unroll
    for (int s = 4; s < 7; ++s)
        #pragma unroll
        for (int j = 0; j < 4; ++j) xg[(s - 4) * 4 + j] = *(const bf16x8*)(Xb + (s * 4 + j) * 512);
    LA(a1, 3);
    MM(a0, &xf[8]);                  // stage 2
    LA(a0, 4);
    MM(a1, &xf[12]);                 // stage 3
    LA(a1, 5);
    MM(a0, &xg[0]);                  // stage 4
    LA(a0, 6);
    MM(a1, &xg[4]);                  // stage 5
    MM(a0, &xg[8]);                  // stage 6

    // per-column scale (validity + 1/sap + frame-norm)
    float invv[4];
    #pragma unroll
    for (int j = 0; j < 4; ++j) invv[j] = invn[b * T_PAD + t0 + wt * 64 + j * 16 + lm];

    // epilogue: 4 rounds x 32 p-rows -> windowed max -> atomicMax(pos)
    int wbase = t0 / STRIDE_;
    int tmax = min(t0 + 128, T_POOL);
    for (int rr = 0; rr < 4; ++rr) {
        __syncthreads();
        if (wp == (rr >> 1)) {
            #pragma unroll
            for (int i2 = 0; i2 < 2; ++i2) {
                int i = (rr & 1) * 2 + i2;
                #pragma unroll
                for (int j = 0; j < 4; ++j) {
                    int col = wt * 64 + j * 16 + lm;
                    #pragma unroll
                    for (int q = 0; q < 4; ++q)
                        Ss[(i2 * 16 + quad * 4 + q) * 132 + col] = acc[i][j][q] * invv[j];
                }
            }
        }
        __syncthreads();
        int sidx = tid & 7, pl = tid >> 3;
        int w = wbase + sidx;
        int tlo = max(w * STRIDE_, t0), thi = min(w * STRIDE_ + STRIDE_, tmax);
        if (w < NWIN && tlo < thi) {
            float m = -3.4e38f;
            for (int t = tlo; t < thi; ++t) m = fmaxf(m, Ss[pl * 132 + (t - t0)]);
            atomicMax(&pos[((size_t)b * P_PAD + p0 + rr * 32 + pl) * NWIN + w], fkey(m));
        }
    }
}

// ---- final: maskgraph on-the-fly (bitmask popcount), coef, fs reduce, norm reduce ----
__global__ void k_out(const unsigned* __restrict__ pos, const int* __restrict__ topn_w,
                      const float* __restrict__ topv_w, const float* __restrict__ W,
                      const float* __restrict__ normt, const float* __restrict__ bcls,
                      float* __restrict__ out)
{
    __shared__ unsigned maskT[N_NODE * 13];
    __shared__ float cf0[P_PAT], cf1[P_PAT];
    __shared__ float sh[512];
    int b = blockIdx.x, tid = threadIdx.x;

    for (int i = tid; i < N_NODE * 13; i += 256) maskT[i] = 0u;
    __syncthreads();
    for (int idx = tid; idx < P_PAT * 3; idx += 256) {
        int q = idx / 3;
        int n = topn_w[idx];
        atomicOr(&maskT[n * 13 + (q >> 5)], 1u << (q & 31));
    }
    __syncthreads();

    for (int p = tid; p < P_PAT; p += 256) {
        int tn[3]; float tv[3];
        #pragma unroll
        for (int i = 0; i < 3; ++i) { tn[i] = topn_w[p * 3 + i]; tv[i] = topv_w[p * 3 + i]; }
        float c0 = 0.f, c1 = 0.f;
        #pragma unroll
        for (int i = 0; i < 3; ++i)
            #pragma unroll
            for (int j = 0; j < 3; ++j) {
                int a = tn[i], bb = tn[j];
                int mgv = 0;
                #pragma unroll
                for (int w = 0; w < 13; ++w)
                    mgv += __popc(maskT[a * 13 + w] & maskT[bb * 13 + w]);
                int nm = a * N_NODE + bb;
                float f = tv[i] * tv[j] / ((float)mgv + 1e-9f);
                c0 += f * W[nm * 2 + 0];
                c1 += f * W[nm * 2 + 1];
            }
        cf0[p] = c0; cf1[p] = c1;
    }
    __syncthreads();
    float s0 = 0.f, s1 = 0.f;
    for (int p = tid; p < P_PAT; p += 256) {
        const unsigned* pp = pos + ((size_t)b * P_PAD + p) * NWIN;
        float fs = 0.f;
        #pragma unroll
        for (int w = 0; w < NWIN; ++w) {
            unsigned k = pp[w];
            unsigned u = (k & 0x80000000u) ? (k ^ 0x80000000u) : ~k;
            fs += __uint_as_float(u);
        }
        s0 += fs * cf0[p];
        s1 += fs * cf1[p];
    }
    sh[tid] = s0; sh[256 + tid] = s1;
    __syncthreads();
    for (int o = 128; o > 0; o >>= 1) {
        if (tid < o) { sh[tid] += sh[tid + o]; sh[256 + tid] += sh[256 + tid + o]; }
        __syncthreads();
    }
    if (tid == 0) {
        out[b * 2 + 0] = sh[0]   + bcls[0];
        out[b * 2 + 1] = sh[256] + bcls[1];
    }
    if (b == 0) {
        __syncthreads();
        float ns = 0.f;
        for (int i = tid; i < P_PAT; i += 256) ns += normt[i];
        sh[tid] = ns;
        __syncthreads();
        for (int o = 128; o > 0; o >>= 1) {
            if (tid < o) sh[tid] += sh[tid + o];
            __syncthreads();
        }
        if (tid == 0) { out[256] = sh[0]; out[257] = 0.f; }
    }
}

extern "C" void kernel_launch(void* const* d_in, const int* in_sizes, int n_in,
                              void* d_out, int out_size, void* d_ws, size_t ws_size,
                              hipStream_t stream) {
    (void)in_sizes; (void)n_in; (void)out_size; (void)ws_size;
    const float* x        = (const float*)d_in[0];
    const int*   length   = (const int*)d_in[1];
    const float* patterns = (const float*)d_in[2];
    const float* Wcls     = (const float*)d_in[3];
    const float* bcls     = (const float*)d_in[4];
    float* out = (float*)d_out;
    char* ws = (char*)d_ws;

    u16*      Ah    = (u16*)(ws + O_AH);
    u16*      XT    = (u16*)(ws + O_XT);
    float*    invn  = (float*)(ws + O_INVN);
    unsigned* pos   = (unsigned*)(ws + O_POS);
    int*      topn  = (int*)(ws + O_TOPN);
    float*    topv  = (float*)(ws + O_TOPV);
    float*    normt = (float*)(ws + O_NORMT);

    k_prep<<<512, 256, 0, stream>>>(x, length, patterns, Ah, XT, invn,
                                    topn, topv, normt, pos);
    k_mm<<<1536, 256, 0, stream>>>(Ah, XT, invn, pos);
    k_out<<<128, 256, 0, stream>>>(pos, topn, topv, Wcls, normt, bcls, out);
}

// Round 10
// 126.964 us; speedup vs baseline: 1.4561x; 1.0761x over previous
//
#include <hip/hip_runtime.h>

#define N_NODE 200
#define T_LEN 360
#define T_POOL 350
#define T_PAD 384
#define P_PAT 400
#define P_PAD 512
#define NWIN 14
#define STRIDE_ 25
#define KPAD 224            // 7 stages x 32

// ---- workspace layout (bytes) ----
#define O_AH    0           // A, MFMA-frag order: [7][8][4][64][8] bf16 = 229376
#define O_XT    229376      // X, B-frag order: [128][6][7][4][4][16][8] bf16 = 22020096
#define O_SSQP  22249472    // [128][7][384] f32 partial ssq = 1376256
#define O_POS   23625728    // [128][512][14] u32 = 3670016 (zeroed in k_prep)
#define O_TOPN  27295744    // [400][3] i32
#define O_TOPV  27300544    // [400][3] f32
#define O_NORMT 27305344    // [400] f32

typedef unsigned short u16;
typedef __attribute__((ext_vector_type(8))) short bf16x8;
typedef __attribute__((ext_vector_type(4))) float f32x4;

__device__ __forceinline__ unsigned fkey(float f) {
    unsigned u = __float_as_uint(f);
    return (u & 0x80000000u) ? ~u : (u | 0x80000000u);
}
__device__ __forceinline__ u16 f2bf(float f) {          // RNE f32->bf16
    unsigned u = __float_as_uint(f);
    unsigned r = u + 0x7FFFu + ((u >> 16) & 1u);
    return (u16)(r >> 16);
}

// ---- prep: pos zero + pattern prep (blk<128) + X transpose, one block per (b,c) ----
__global__ __launch_bounds__(256) void k_prep(
    const float* __restrict__ x, const float* __restrict__ pat,
    u16* __restrict__ Ah, u16* __restrict__ XT, float* __restrict__ ssqp,
    int* __restrict__ topn_w, float* __restrict__ topv_w, float* __restrict__ normt,
    unsigned* __restrict__ pos)
{
    __shared__ unsigned ldsw[16 * 388];   // k-pair rows x t, pitch 388
    int blk = blockIdx.x, tid = threadIdx.x;

    {   // zero pos: 917504 u32 over 1024 blocks
        int idx = blk * 256 + tid;
        #pragma unroll
        for (int i = 0; i < 4; ++i) {
            int w = idx + i * 262144;
            if (w < 917504) pos[w] = 0u;
        }
    }

    if (blk < 128) {
        // ---- pattern prep: 4 waves, one pattern each ----
        int lane = tid & 63;
        int p = blk * 4 + (tid >> 6);     // 0..511
        bool pv = p < P_PAT;
        float sv[4], av[4];
        int nn[4];
        float ss = 0.f;
        #pragma unroll
        for (int j = 0; j < 4; ++j) {
            int n = lane + 64 * j;
            nn[j] = n;
            if (pv && n < N_NODE) { float v = pat[p * N_NODE + n]; sv[j] = v; av[j] = fabsf(v); ss += v * v; }
            else { sv[j] = 0.f; av[j] = -1.f; }
        }
        #pragma unroll
        for (int off = 32; off >= 1; off >>= 1) ss += __shfl_xor(ss, off);
        float rn = 1.0f / sqrtf(ss + 1e-9f);

        int pb = p >> 6, ii = (p >> 4) & 3, plm = p & 15;
        #pragma unroll
        for (int j = 0; j < 4; ++j) {
            int n = nn[j];
            if (n < KPAD) {
                float v = (pv && n < N_NODE) ? sv[j] * rn : 0.f;
                int s = n >> 5, c = n & 31, quad = c >> 3, e = c & 7;
                size_t idx = ((size_t)((s * 8 + pb) * 4 + ii) * 64 + quad * 16 + plm) * 8 + e;
                Ah[idx] = f2bf(v);
            }
        }
        if (!pv) return;

        int topn[3]; float topv[3];
        for (int r = 0; r < 3; ++r) {
            float bv = -2.f; int bi = 1 << 30;
            #pragma unroll
            for (int j = 0; j < 4; ++j)
                if (av[j] > bv || (av[j] == bv && nn[j] < bi)) { bv = av[j]; bi = nn[j]; }
            #pragma unroll
            for (int off = 32; off >= 1; off >>= 1) {
                float ov = __shfl_xor(bv, off); int oi = __shfl_xor(bi, off);
                if (ov > bv || (ov == bv && oi < bi)) { bv = ov; bi = oi; }
            }
            int jj = bi >> 6, src = bi & 63;
            float rawj = (jj == 0) ? sv[0] : (jj == 1) ? sv[1] : (jj == 2) ? sv[2] : sv[3];
            float raw = __shfl(rawj, src);
            topn[r] = bi; topv[r] = raw * rn;
            #pragma unroll
            for (int j = 0; j < 4; ++j) if (nn[j] == bi) av[j] = -1.f;
        }
        float fullnorm = sqrtf(ss) * rn;
        float topnorm = sqrtf(topv[0]*topv[0] + topv[1]*topv[1] + topv[2]*topv[2]);
        if (lane == 0) {
            float d = 1.0f - topnorm / fullnorm;
            normt[p] = d * d * (1.0f / 800.0f);
        }
        if (lane < 3) { topn_w[p * 3 + lane] = topn[lane]; topv_w[p * 3 + lane] = topv[lane]; }
        return;
    }

    // ---- X transpose: block (b, c) handles k-chunk c (32 k) over all t ----
    int bc = blk - 128;                   // 0..895
    int b = bc / 7, c = bc - 7 * b;
    int k0 = c * 32;
    const float* xb = x + (size_t)b * (N_NODE * T_LEN);
    bool tok2 = tid < (T_LEN - 256);      // t2 = 256+tid valid load
    float ssq0 = 0.f, ssq1 = 0.f;

    #pragma unroll
    for (int kkp = 0; kkp < 16; ++kkp) {
        int k = k0 + 2 * kkp;
        bool kv0 = k < N_NODE, kv1 = (k + 1) < N_NODE;
        float v0 = kv0 ? xb[k * T_LEN + tid]             : 0.f;
        float v1 = kv1 ? xb[(k + 1) * T_LEN + tid]       : 0.f;
        float w0 = (kv0 && tok2) ? xb[k * T_LEN + 256 + tid]       : 0.f;
        float w1 = (kv1 && tok2) ? xb[(k + 1) * T_LEN + 256 + tid] : 0.f;
        ssq0 = fmaf(v0, v0, fmaf(v1, v1, ssq0));
        ssq1 = fmaf(w0, w0, fmaf(w1, w1, ssq1));
        ldsw[kkp * 388 + tid] = (unsigned)f2bf(v0) | ((unsigned)f2bf(v1) << 16);
        if (tid < 128)
            ldsw[kkp * 388 + 256 + tid] = (unsigned)f2bf(w0) | ((unsigned)f2bf(w1) << 16);
    }
    // partial ssq for this chunk (plain writes, k_mm sums the 7)
    ssqp[(size_t)(b * 7 + c) * 384 + tid] = ssq0;
    if (tid < 128) ssqp[(size_t)(b * 7 + c) * 384 + 256 + tid] = ssq1;
    __syncthreads();

    // frag-order write-out: 1536 units of 16B, 6 per thread; t>=360 -> zeros
    #pragma unroll
    for (int i = 0; i < 6; ++i) {
        int u = i * 256 + tid;
        int lm = u & 15, q = (u >> 4) & 3, j = (u >> 6) & 3, tb = u >> 8;
        int t = tb * 64 + j * 16 + lm;
        uint4 val;
        if (t < T_LEN)
            val = make_uint4(ldsw[(q * 4 + 0) * 388 + t], ldsw[(q * 4 + 1) * 388 + t],
                             ldsw[(q * 4 + 2) * 388 + t], ldsw[(q * 4 + 3) * 388 + t]);
        else
            val = make_uint4(0u, 0u, 0u, 0u);
        *(uint4*)&XT[(size_t)(b * 6 + tb) * 14336 + (size_t)(c * 4 + j) * 512 + q * 128 + lm * 8] = val;
    }
}

// ---- MFMA GEMM: barrier-free K-loop, all frags coalesced 1KB/wave from global ----
__global__ __launch_bounds__(256, 2) void k_mm(
    const u16* __restrict__ Ah, const u16* __restrict__ XT,
    const float* __restrict__ ssqp, const int* __restrict__ length,
    unsigned* __restrict__ pos)
{
    __shared__ __align__(16) float Ss[16 * 132];
    int tid = threadIdx.x, blk = blockIdx.x;
    // XCD co-location: 12 blocks of each b congruent mod 8
    int xcd = blk & 7, slot = blk >> 3;
    int g = slot / 12, r = slot - 12 * g;
    int b = xcd + 8 * g;
    int t0 = (r % 3) * 128;
    int p0 = (r / 3) * 128;
    int lane = tid & 63, wid = tid >> 6;
    int quad = lane >> 4, lm = lane & 15;
    int wp = wid >> 1, wt = wid & 1;
    int pbq = (p0 >> 6) + wp;
    int tb = (t0 >> 6) + wt;

    const u16* Ab = Ah + (size_t)pbq * 2048 + lane * 8;           // + s*16384 + i*512
    const u16* Xb = XT + (size_t)(b * 6 + tb) * 14336 + lane * 8; // + (s*4+j)*512

    f32x4 acc[4][4];
    #pragma unroll
    for (int i = 0; i < 4; ++i)
        #pragma unroll
        for (int j = 0; j < 4; ++j) acc[i][j] = (f32x4){0.f, 0.f, 0.f, 0.f};

    auto LA = [&](bf16x8* d, int s) {
        const u16* p = Ab + (size_t)s * 16384;
        #pragma unroll
        for (int i = 0; i < 4; ++i) d[i] = *(const bf16x8*)(p + i * 512);
    };
    auto MM = [&](bf16x8* a, bf16x8* xv) {
        #pragma unroll
        for (int i = 0; i < 4; ++i)
            #pragma unroll
            for (int j = 0; j < 4; ++j)
                acc[i][j] = __builtin_amdgcn_mfma_f32_16x16x32_bf16(a[i], xv[j], acc[i][j], 0, 0, 0);
    };

    bf16x8 a0[4], a1[4], xf[16], xg[12];
    LA(a0, 0);
    #pragma unroll
    for (int s = 0; s < 4; ++s)
        #pragma unroll
        for (int j = 0; j < 4; ++j) xf[s * 4 + j] = *(const bf16x8*)(Xb + (s * 4 + j) * 512);
    LA(a1, 1);
    MM(a0, &xf[0]);                  // stage 0
    LA(a0, 2);
    MM(a1, &xf[4]);                  // stage 1
    #pragma unroll
    for (int s = 4; s < 7; ++s)
        #pragma unroll
        for (int j = 0; j < 4; ++j) xg[(s - 4) * 4 + j] = *(const bf16x8*)(Xb + (s * 4 + j) * 512);
    LA(a1, 3);
    MM(a0, &xf[8]);                  // stage 2
    LA(a0, 4);
    MM(a1, &xf[12]);                 // stage 3
    LA(a1, 5);
    MM(a0, &xg[0]);                  // stage 4
    LA(a0, 6);
    MM(a1, &xg[4]);                  // stage 5
    MM(a0, &xg[8]);                  // stage 6

    // per-column scale: sum 7 ssq partials, fold validity + 1/sap
    int sap = length[b] / STRIDE_;
    int tvalid = sap * STRIDE_;
    float invv[4];
    #pragma unroll
    for (int j = 0; j < 4; ++j) {
        int t = t0 + wt * 64 + j * 16 + lm;
        float tot = 0.f;
        #pragma unroll
        for (int c = 0; c < 7; ++c) tot += ssqp[(size_t)(b * 7 + c) * 384 + t];
        invv[j] = (t < tvalid) ? 1.0f / (sqrtf(tot + 1e-9f) * (float)sap) : 0.f;
    }

    // epilogue: 4 rounds x 32 p-rows -> windowed max -> atomicMax(pos)
    int wbase = t0 / STRIDE_;
    int tmax = min(t0 + 128, T_POOL);
    for (int rr = 0; rr < 4; ++rr) {
        __syncthreads();
        if (wp == (rr >> 1)) {
            #pragma unroll
            for (int i2 = 0; i2 < 2; ++i2) {
                int i = (rr & 1) * 2 + i2;
                #pragma unroll
                for (int j = 0; j < 4; ++j) {
                    int col = wt * 64 + j * 16 + lm;
                    #pragma unroll
                    for (int q = 0; q < 4; ++q)
                        Ss[(i2 * 16 + quad * 4 + q) * 132 + col] = acc[i][j][q] * invv[j];
                }
            }
        }
        __syncthreads();
        int sidx = tid & 7, pl = tid >> 3;
        int w = wbase + sidx;
        int tlo = max(w * STRIDE_, t0), thi = min(w * STRIDE_ + STRIDE_, tmax);
        if (w < NWIN && tlo < thi) {
            float m = -3.4e38f;
            for (int t = tlo; t < thi; ++t) m = fmaxf(m, Ss[pl * 132 + (t - t0)]);
            atomicMax(&pos[((size_t)b * P_PAD + p0 + rr * 32 + pl) * NWIN + w], fkey(m));
        }
    }
}

// ---- final: maskgraph on-the-fly (bitmask popcount), coef, fs reduce, norm reduce ----
__global__ void k_out(const unsigned* __restrict__ pos, const int* __restrict__ topn_w,
                      const float* __restrict__ topv_w, const float* __restrict__ W,
                      const float* __restrict__ normt, const float* __restrict__ bcls,
                      float* __restrict__ out)
{
    __shared__ unsigned maskT[N_NODE * 13];
    __shared__ float cf0[P_PAT], cf1[P_PAT];
    __shared__ float sh[512];
    int b = blockIdx.x, tid = threadIdx.x;

    for (int i = tid; i < N_NODE * 13; i += 256) maskT[i] = 0u;
    __syncthreads();
    for (int idx = tid; idx < P_PAT * 3; idx += 256) {
        int q = idx / 3;
        int n = topn_w[idx];
        atomicOr(&maskT[n * 13 + (q >> 5)], 1u << (q & 31));
    }
    __syncthreads();

    for (int p = tid; p < P_PAT; p += 256) {
        int tn[3]; float tv[3];
        #pragma unroll
        for (int i = 0; i < 3; ++i) { tn[i] = topn_w[p * 3 + i]; tv[i] = topv_w[p * 3 + i]; }
        float c0 = 0.f, c1 = 0.f;
        #pragma unroll
        for (int i = 0; i < 3; ++i)
            #pragma unroll
            for (int j = 0; j < 3; ++j) {
                int a = tn[i], bb = tn[j];
                int mgv = 0;
                #pragma unroll
                for (int w = 0; w < 13; ++w)
                    mgv += __popc(maskT[a * 13 + w] & maskT[bb * 13 + w]);
                int nm = a * N_NODE + bb;
                float f = tv[i] * tv[j] / ((float)mgv + 1e-9f);
                c0 += f * W[nm * 2 + 0];
                c1 += f * W[nm * 2 + 1];
            }
        cf0[p] = c0; cf1[p] = c1;
    }
    __syncthreads();
    float s0 = 0.f, s1 = 0.f;
    for (int p = tid; p < P_PAT; p += 256) {
        const unsigned* pp = pos + ((size_t)b * P_PAD + p) * NWIN;
        float fs = 0.f;
        #pragma unroll
        for (int w = 0; w < NWIN; ++w) {
            unsigned k = pp[w];
            unsigned u = (k & 0x80000000u) ? (k ^ 0x80000000u) : ~k;
            fs += __uint_as_float(u);
        }
        s0 += fs * cf0[p];
        s1 += fs * cf1[p];
    }
    sh[tid] = s0; sh[256 + tid] = s1;
    __syncthreads();
    for (int o = 128; o > 0; o >>= 1) {
        if (tid < o) { sh[tid] += sh[tid + o]; sh[256 + tid] += sh[256 + tid + o]; }
        __syncthreads();
    }
    if (tid == 0) {
        out[b * 2 + 0] = sh[0]   + bcls[0];
        out[b * 2 + 1] = sh[256] + bcls[1];
    }
    if (b == 0) {
        __syncthreads();
        float ns = 0.f;
        for (int i = tid; i < P_PAT; i += 256) ns += normt[i];
        sh[tid] = ns;
        __syncthreads();
        for (int o = 128; o > 0; o >>= 1) {
            if (tid < o) sh[tid] += sh[tid + o];
            __syncthreads();
        }
        if (tid == 0) { out[256] = sh[0]; out[257] = 0.f; }
    }
}

extern "C" void kernel_launch(void* const* d_in, const int* in_sizes, int n_in,
                              void* d_out, int out_size, void* d_ws, size_t ws_size,
                              hipStream_t stream) {
    (void)in_sizes; (void)n_in; (void)out_size; (void)ws_size;
    const float* x        = (const float*)d_in[0];
    const int*   length   = (const int*)d_in[1];
    const float* patterns = (const float*)d_in[2];
    const float* Wcls     = (const float*)d_in[3];
    const float* bcls     = (const float*)d_in[4];
    float* out = (float*)d_out;
    char* ws = (char*)d_ws;

    u16*      Ah    = (u16*)(ws + O_AH);
    u16*      XT    = (u16*)(ws + O_XT);
    float*    ssqp  = (float*)(ws + O_SSQP);
    unsigned* pos   = (unsigned*)(ws + O_POS);
    int*      topn  = (int*)(ws + O_TOPN);
    float*    topv  = (float*)(ws + O_TOPV);
    float*    normt = (float*)(ws + O_NORMT);

    k_prep<<<1024, 256, 0, stream>>>(x, patterns, Ah, XT, ssqp,
                                     topn, topv, normt, pos);
    k_mm<<<1536, 256, 0, stream>>>(Ah, XT, ssqp, length, pos);
    k_out<<<128, 256, 0, stream>>>(pos, topn, topv, Wcls, normt, bcls, out);
}